// Round 5
// baseline (87.020 us; speedup 1.0000x reference)
//
#include <hip/hip_runtime.h>

#define S_LEN 2048
#define D_DIM 256
#define WIN 33
#define HALF 16
#define VR_STRIDE 266   // shorts; q4-step = 8*133 dwords = 8 mod 32 -> 32 distinct banks on PV gathers
#define SC_STRIDE 68    // f32
#define PT_STRIDE 72    // shorts; b128 frag reads 16B-aligned

typedef __attribute__((ext_vector_type(8))) short short8_t;
typedef __attribute__((ext_vector_type(4))) float f32x4;

__device__ inline unsigned short f32_to_bf16(float f) {
    unsigned u = __float_as_uint(f);
    return (unsigned short)((u + 0x7fffu + ((u >> 16) & 1u)) >> 16);  // RNE
}
// two f32 -> packed bf16x2, round-half-away: 2 adds + 1 v_perm
__device__ inline unsigned pack2_bf16(float lo, float hi) {
    unsigned a = __float_as_uint(lo) + 0x8000u;
    unsigned b = __float_as_uint(hi) + 0x8000u;
    return __builtin_amdgcn_perm(b, a, 0x07060302);
}
__device__ inline short8_t pack_bf16x8(float4 x, float4 y) {
    union { unsigned u[4]; short8_t s; } r;
    r.u[0] = pack2_bf16(x.x, x.y); r.u[1] = pack2_bf16(x.z, x.w);
    r.u[2] = pack2_bf16(y.x, y.y); r.u[3] = pack2_bf16(y.z, y.w);
    return r.s;
}

// Block = 16 query rows, 256 threads = 4 waves (2048 waves total -> 2/SIMD).
// Pre-barrier: all threads stage V (coalesced float4 -> bf16 LDS row-major);
//              waves 0..2 compute one 16x16 QK col-tile each (span cols 0..47;
//              cols 48..63 are always out-of-band -> skipped).
// Softmax: 16 threads/row over the 64-col score row (b128 read, 8 shuffles).
// PV: wave w -> output D-slice [64w, 64w+64), B-frags gathered from LDS.
__global__ __launch_bounds__(256) void local_attn_v5(
    const float* __restrict__ q,
    const float* __restrict__ k,
    const float* __restrict__ v,
    const int*   __restrict__ mask,
    float* __restrict__ out_v,   // [B*S*D]
    float* __restrict__ out_p)   // [B*S*WIN]
{
    __shared__ __align__(16) unsigned short Vr[48 * VR_STRIDE];  // 25.5 KB
    __shared__ __align__(16) float          Sc[16 * SC_STRIDE];  // 4.25 KB
    __shared__ __align__(16) unsigned short Pt[16 * PT_STRIDE];  // 2.25 KB
    __shared__ int wm[64];

    const int t    = threadIdx.x;
    const int lane = t & 63;
    const int w    = t >> 6;         // wave 0..3
    const int l15  = lane & 15;
    const int q4   = lane >> 4;

    const int bid  = blockIdx.x;               // 0..511
    const int tile = ((bid & 7) << 6) | (bid >> 3);   // XCD-contiguous stripes
    const int b    = tile >> 7;
    const int s0   = (tile & 127) << 4;

    const float* qb = q + ((size_t)b * S_LEN + s0) * D_DIM;
    const float* kb = k + (size_t)b * S_LEN * D_DIM;
    const float* vb = v + (size_t)b * S_LEN * D_DIM;

    // ---- V staging loads: 48 rows x 64 float4, coalesced, 12 per thread ----
    float4 vreg[12];
#pragma unroll
    for (int it = 0; it < 12; ++it) {
        const int lin = it * 256 + t;
        const int g   = lin >> 6;        // span row 0..47
        const int c4  = lin & 63;        // float4 col
        const int idx = min(max(s0 - HALF + g, 0), S_LEN - 1);
        vreg[it] = *(const float4*)(vb + (size_t)idx * D_DIM + c4 * 4);
    }
    if (t < 64) {
        const int idx = s0 - HALF + t;
        wm[t] = (idx >= 0 && idx < S_LEN) ? (mask[b * S_LEN + idx] != 0) : 0;
    }

    // ---- QK^T: waves 0..2, col-tile c = 16w + l15 (real span = 48) ----
    if (w < 3) {
        const int c    = 16 * w + l15;
        const int kidx = min(max(s0 - HALF + c, 0), S_LEN - 1);
        const float* kr = kb + (size_t)kidx * D_DIM;
        const float* qr = qb + l15 * D_DIM;
        f32x4 acc = (f32x4){0.f, 0.f, 0.f, 0.f};
#pragma unroll
        for (int ks = 0; ks < 8; ++ks) {
            const float* pq = qr + ks * 32 + q4 * 8;
            const float* pk = kr + ks * 32 + q4 * 8;
            const short8_t aq = pack_bf16x8(*(const float4*)pq, *(const float4*)(pq + 4));
            const short8_t bk = pack_bf16x8(*(const float4*)pk, *(const float4*)(pk + 4));
            acc = __builtin_amdgcn_mfma_f32_16x16x32_bf16(aq, bk, acc, 0, 0, 0);
        }
#pragma unroll
        for (int r = 0; r < 4; ++r)
            Sc[(q4 * 4 + r) * SC_STRIDE + c] = acc[r];
    }

    // ---- V pack -> LDS row-major bf16 ----
#pragma unroll
    for (int it = 0; it < 12; ++it) {
        const int lin = it * 256 + t;
        const int g   = lin >> 6;
        const int c4  = lin & 63;
        const unsigned u0 = pack2_bf16(vreg[it].x, vreg[it].y);
        const unsigned u1 = pack2_bf16(vreg[it].z, vreg[it].w);
        *(unsigned*)&Vr[g * VR_STRIDE + c4 * 4]     = u0;
        *(unsigned*)&Vr[g * VR_STRIDE + c4 * 4 + 2] = u1;
    }
    __syncthreads();

    // ---- softmax: row = t>>4, thread covers cols 4e..4e+3 ----
    {
        const int row = t >> 4;
        const int e   = t & 15;
        float vs[4], ps[4];
        if (e < 12) {                      // cols >= 48 are always out-of-band
            const float4 s4 = *(const float4*)&Sc[row * SC_STRIDE + 4 * e];
            const float sarr[4] = {s4.x, s4.y, s4.z, s4.w};
#pragma unroll
            for (int kq = 0; kq < 4; ++kq) {
                const int c = 4 * e + kq, j = c - row;
                const bool inb = (j >= 0) && (j < WIN);
                vs[kq] = inb ? (wm[c] ? sarr[kq] * 0.0625f : -1e10f) : -1e30f;
            }
        } else {
#pragma unroll
            for (int kq = 0; kq < 4; ++kq) vs[kq] = -1e30f;
        }
        float m = fmaxf(fmaxf(vs[0], vs[1]), fmaxf(vs[2], vs[3]));
        m = fmaxf(m, __shfl_xor(m, 1, 64));
        m = fmaxf(m, __shfl_xor(m, 2, 64));
        m = fmaxf(m, __shfl_xor(m, 4, 64));
        m = fmaxf(m, __shfl_xor(m, 8, 64));
        float s = 0.f;
#pragma unroll
        for (int kq = 0; kq < 4; ++kq) { vs[kq] = __expf(vs[kq] - m); s += vs[kq]; }
        s += __shfl_xor(s, 1, 64);
        s += __shfl_xor(s, 2, 64);
        s += __shfl_xor(s, 4, 64);
        s += __shfl_xor(s, 8, 64);
        const float rinv = 1.0f / s;
        union { unsigned short u[4]; uint2 d; } pw;
#pragma unroll
        for (int kq = 0; kq < 4; ++kq) {
            ps[kq]   = vs[kq] * rinv;
            pw.u[kq] = f32_to_bf16(ps[kq]);
        }
        *(uint2*)&Pt[row * PT_STRIDE + 4 * e] = pw.d;   // 8B-aligned
        float* prow = out_p + ((size_t)(b * S_LEN + s0 + row)) * WIN;
#pragma unroll
        for (int kq = 0; kq < 4; ++kq) {
            const int j = 4 * e + kq - row;
            if (j >= 0 && j < WIN) prow[j] = ps[kq];
        }
    }
    __syncthreads();

    // ---- PV: wave w -> D cols [64w, 64w+64) ----
    const short8_t ap0 = *(const short8_t*)&Pt[l15 * PT_STRIDE + q4 * 8];
    const short8_t ap1 = *(const short8_t*)&Pt[l15 * PT_STRIDE + 32 + q4 * 8];
    float* ob = out_v + ((size_t)b * S_LEN + s0) * D_DIM;
#pragma unroll
    for (int nt = 0; nt < 4; ++nt) {
        const int d = 64 * w + 16 * nt + l15;
        short8_t b0, b1;
#pragma unroll
        for (int j = 0; j < 8; ++j)
            b0[j] = (short)Vr[(q4 * 8 + j) * VR_STRIDE + d];      // g 0..31
#pragma unroll
        for (int j = 0; j < 8; ++j) {
            const int g = min(32 + q4 * 8 + j, 47);               // g>=48: P=0
            b1[j] = (short)Vr[g * VR_STRIDE + d];
        }
        f32x4 acc = (f32x4){0.f, 0.f, 0.f, 0.f};
        acc = __builtin_amdgcn_mfma_f32_16x16x32_bf16(ap0, b0, acc, 0, 0, 0);
        acc = __builtin_amdgcn_mfma_f32_16x16x32_bf16(ap1, b1, acc, 0, 0, 0);
#pragma unroll
        for (int r = 0; r < 4; ++r)
            ob[(size_t)(q4 * 4 + r) * D_DIM + d] = acc[r];
    }
}

extern "C" void kernel_launch(void* const* d_in, const int* in_sizes, int n_in,
                              void* d_out, int out_size, void* d_ws, size_t ws_size,
                              hipStream_t stream) {
    const float* q    = (const float*)d_in[0];
    const float* k    = (const float*)d_in[1];
    const float* v    = (const float*)d_in[2];
    const int*   mask = (const int*)d_in[3];

    const int B = 4;
    float* out_v = (float*)d_out;
    float* out_p = (float*)d_out + (size_t)B * S_LEN * D_DIM;

    const int blocks = B * (S_LEN / 16);    // 512 blocks x 256 threads
    local_attn_v5<<<blocks, 256, 0, stream>>>(q, k, v, mask, out_v, out_p);
}

// Round 6
// 83.532 us; speedup vs baseline: 1.0417x; 1.0417x over previous
//
#include <hip/hip_runtime.h>

#define S_LEN 2048
#define D_DIM 256
#define WIN 33
#define HALF 16
#define TROWS 32
#define SPAN 64
#define SC_STRIDE 68    // f32
#define PT_STRIDE 72    // shorts; row pitch 144 B = 9*16 -> b128 reads aligned

typedef __attribute__((ext_vector_type(8))) short short8_t;
typedef __attribute__((ext_vector_type(4))) float f32x4;

__device__ inline unsigned short f32_to_bf16(float f) {
    unsigned u = __float_as_uint(f);
    return (unsigned short)((u + 0x7fffu + ((u >> 16) & 1u)) >> 16);  // RNE
}
// two f32 -> packed bf16x2, round-half-away: 2 adds + 1 v_perm
__device__ inline unsigned pack2_bf16(float lo, float hi) {
    unsigned a = __float_as_uint(lo) + 0x8000u;
    unsigned b = __float_as_uint(hi) + 0x8000u;
    return __builtin_amdgcn_perm(b, a, 0x07060302);
}
__device__ inline short8_t pack_bf16x8(float4 x, float4 y) {
    union { unsigned u[4]; short8_t s; } r;
    r.u[0] = pack2_bf16(x.x, x.y); r.u[1] = pack2_bf16(x.z, x.w);
    r.u[2] = pack2_bf16(y.x, y.y); r.u[3] = pack2_bf16(y.z, y.w);
    return r.s;
}

// Block = 32 query rows (span 64), 512 threads = 8 waves; 256 blocks = 1/CU,
// 2 waves/SIMD. Halo redundancy 2x (vs 3x for 16-row tiles) -> ~40 MB L2 fill.
// Phase A: wave w computes QK 16x16 tile (rt=w>>2, ct=w&3) from global;
//          then preloads its PV V-operands (64 scalars/lane) into registers.
// Phase B: softmax, 16 threads/row; P -> bf16 LDS; p_attn stored.
// Phase C: PV from registers+LDS only; wave w -> rows rt*16.., D-slice (w&3)*64..
__global__ __launch_bounds__(512) void local_attn_v6(
    const float* __restrict__ q,
    const float* __restrict__ k,
    const float* __restrict__ v,
    const int*   __restrict__ mask,
    float* __restrict__ out_v,   // [B*S*D]
    float* __restrict__ out_p)   // [B*S*WIN]
{
    __shared__ __align__(16) float          Sc[TROWS * SC_STRIDE];  // 8.7 KB
    __shared__ __align__(16) unsigned short Pt[TROWS * PT_STRIDE];  // 4.6 KB
    __shared__ int wm[SPAN];

    const int t    = threadIdx.x;
    const int lane = t & 63;
    const int w    = t >> 6;          // wave 0..7
    const int l15  = lane & 15;
    const int q4   = lane >> 4;
    const int rt   = w >> 2;          // row-tile 0..1 (QK and PV)
    const int wq   = w & 3;           // col-tile (QK) / D-slice (PV)

    const int bid  = blockIdx.x;                      // 0..255
    const int tile = ((bid & 7) << 5) | (bid >> 3);   // XCD-contiguous stripes
    const int b    = tile >> 6;                       // 64 tiles per batch
    const int s0   = (tile & 63) << 5;                // first query row

    const float* qb = q + ((size_t)b * S_LEN + s0) * D_DIM;
    const float* kb = k + (size_t)b * S_LEN * D_DIM;
    const float* vb = v + (size_t)b * S_LEN * D_DIM;

    if (t < SPAN) {
        const int idx = s0 - HALF + t;
        wm[t] = (idx >= 0 && idx < S_LEN) ? (mask[b * S_LEN + idx] != 0) : 0;
    }

    // ---- Phase A1: QK 16x16 tile per wave ----
    {
        const int c    = wq * 16 + l15;                       // span col
        const int kidx = min(max(s0 - HALF + c, 0), S_LEN - 1);
        const float* kr = kb + (size_t)kidx * D_DIM;
        const float* qr = qb + (size_t)(rt * 16 + l15) * D_DIM;
        f32x4 acc = (f32x4){0.f, 0.f, 0.f, 0.f};
#pragma unroll
        for (int ks = 0; ks < 8; ++ks) {
            const float* pq = qr + ks * 32 + q4 * 8;
            const float* pk = kr + ks * 32 + q4 * 8;
            const short8_t aq = pack_bf16x8(*(const float4*)pq, *(const float4*)(pq + 4));
            const short8_t bk = pack_bf16x8(*(const float4*)pk, *(const float4*)(pk + 4));
            acc = __builtin_amdgcn_mfma_f32_16x16x32_bf16(aq, bk, acc, 0, 0, 0);
        }
#pragma unroll
        for (int r = 0; r < 4; ++r)
            Sc[(rt * 16 + q4 * 4 + r) * SC_STRIDE + c] = acc[r];
    }

    // ---- Phase A2: PV V-operand preload (independent of P) ----
    // B-frag[dct][ks][j] = V[g = ks*32 + q4*8 + j][d = wq*64 + dct*16 + l15]
    short8_t bv[4][2];
    {
        float vr[4][2][8];
#pragma unroll
        for (int dct = 0; dct < 4; ++dct) {
            const int d = wq * 64 + dct * 16 + l15;
#pragma unroll
            for (int ks = 0; ks < 2; ++ks)
#pragma unroll
                for (int j = 0; j < 8; ++j) {
                    const int g   = ks * 32 + q4 * 8 + j;
                    const int idx = min(max(s0 - HALF + g, 0), S_LEN - 1);
                    vr[dct][ks][j] = vb[(size_t)idx * D_DIM + d];
                }
        }
#pragma unroll
        for (int dct = 0; dct < 4; ++dct)
#pragma unroll
            for (int ks = 0; ks < 2; ++ks) {
                float4 x, y;
                x.x = vr[dct][ks][0]; x.y = vr[dct][ks][1];
                x.z = vr[dct][ks][2]; x.w = vr[dct][ks][3];
                y.x = vr[dct][ks][4]; y.y = vr[dct][ks][5];
                y.z = vr[dct][ks][6]; y.w = vr[dct][ks][7];
                bv[dct][ks] = pack_bf16x8(x, y);
            }
    }
    __syncthreads();

    // ---- Phase B: softmax, row = t>>4 (0..31), thread covers cols 4e..4e+3 ----
    {
        const int row = t >> 4;
        const int e   = t & 15;
        const float4 s4 = *(const float4*)&Sc[row * SC_STRIDE + 4 * e];
        const float sarr[4] = {s4.x, s4.y, s4.z, s4.w};
        float vs[4];
#pragma unroll
        for (int kq = 0; kq < 4; ++kq) {
            const int c = 4 * e + kq;
            const int j = c - row;                       // window offset 0..32
            const bool inb = (j >= 0) && (j < WIN);
            vs[kq] = inb ? (wm[c] ? sarr[kq] * 0.0625f : -1e10f) : -1e30f;
        }
        float m = fmaxf(fmaxf(vs[0], vs[1]), fmaxf(vs[2], vs[3]));
        m = fmaxf(m, __shfl_xor(m, 1, 64));
        m = fmaxf(m, __shfl_xor(m, 2, 64));
        m = fmaxf(m, __shfl_xor(m, 4, 64));
        m = fmaxf(m, __shfl_xor(m, 8, 64));
        float s = 0.f;
#pragma unroll
        for (int kq = 0; kq < 4; ++kq) { vs[kq] = __expf(vs[kq] - m); s += vs[kq]; }
        s += __shfl_xor(s, 1, 64);
        s += __shfl_xor(s, 2, 64);
        s += __shfl_xor(s, 4, 64);
        s += __shfl_xor(s, 8, 64);
        const float rinv = 1.0f / s;

        float ps[4];
        union { unsigned short u[4]; uint2 d2; } pw;
#pragma unroll
        for (int kq = 0; kq < 4; ++kq) {
            ps[kq]   = vs[kq] * rinv;                    // 0 outside band
            pw.u[kq] = f32_to_bf16(ps[kq]);
        }
        *(uint2*)&Pt[row * PT_STRIDE + 4 * e] = pw.d2;   // 8B-aligned
        float* prow = out_p + ((size_t)(b * S_LEN + s0 + row)) * WIN;
#pragma unroll
        for (int kq = 0; kq < 4; ++kq) {
            const int j = 4 * e + kq - row;
            if (j >= 0 && j < WIN) prow[j] = ps[kq];
        }
    }
    __syncthreads();

    // ---- Phase C: PV. Wave w -> rows [rt*16, rt*16+16), D [wq*64, wq*64+64) ----
    {
        const short8_t ap0 = *(const short8_t*)&Pt[(rt * 16 + l15) * PT_STRIDE + q4 * 8];
        const short8_t ap1 = *(const short8_t*)&Pt[(rt * 16 + l15) * PT_STRIDE + 32 + q4 * 8];
        float* ob = out_v + ((size_t)b * S_LEN + s0) * D_DIM;
#pragma unroll
        for (int dct = 0; dct < 4; ++dct) {
            f32x4 acc = (f32x4){0.f, 0.f, 0.f, 0.f};
            acc = __builtin_amdgcn_mfma_f32_16x16x32_bf16(ap0, bv[dct][0], acc, 0, 0, 0);
            acc = __builtin_amdgcn_mfma_f32_16x16x32_bf16(ap1, bv[dct][1], acc, 0, 0, 0);
            const int d = wq * 64 + dct * 16 + l15;
#pragma unroll
            for (int r = 0; r < 4; ++r)
                ob[(size_t)(rt * 16 + q4 * 4 + r) * D_DIM + d] = acc[r];
        }
    }
}

extern "C" void kernel_launch(void* const* d_in, const int* in_sizes, int n_in,
                              void* d_out, int out_size, void* d_ws, size_t ws_size,
                              hipStream_t stream) {
    const float* q    = (const float*)d_in[0];
    const float* k    = (const float*)d_in[1];
    const float* v    = (const float*)d_in[2];
    const int*   mask = (const int*)d_in[3];

    const int B = 4;
    float* out_v = (float*)d_out;
    float* out_p = (float*)d_out + (size_t)B * S_LEN * D_DIM;

    const int blocks = B * (S_LEN / TROWS);   // 256 blocks x 512 threads
    local_attn_v6<<<blocks, 512, 0, stream>>>(q, k, v, mask, out_v, out_p);
}

// Round 7
// 83.251 us; speedup vs baseline: 1.0453x; 1.0034x over previous
//
#include <hip/hip_runtime.h>

#define S_LEN 2048
#define D_DIM 256
#define WIN 33
#define HALF 16
#define TROWS 16
#define SPAN 48         // cols 48..63 of the 64-wide frame are always out-of-band
#define SC_STRIDE 68    // f32
#define PT_STRIDE 72    // shorts; row pitch 144 B -> b128 frag reads 16B-aligned

typedef __attribute__((ext_vector_type(8))) short short8_t;
typedef __attribute__((ext_vector_type(4))) float f32x4;

__device__ inline unsigned short f32_to_bf16(float f) {
    unsigned u = __float_as_uint(f);
    return (unsigned short)((u + 0x7fffu + ((u >> 16) & 1u)) >> 16);  // RNE
}
// two f32 -> packed bf16x2, round-half-away: 2 adds + 1 v_perm
__device__ inline unsigned pack2_bf16(float lo, float hi) {
    unsigned a = __float_as_uint(lo) + 0x8000u;
    unsigned b = __float_as_uint(hi) + 0x8000u;
    return __builtin_amdgcn_perm(b, a, 0x07060302);
}
__device__ inline short8_t pack_bf16x8(float4 x, float4 y) {
    union { unsigned u[4]; short8_t s; } r;
    r.u[0] = pack2_bf16(x.x, x.y); r.u[1] = pack2_bf16(x.z, x.w);
    r.u[2] = pack2_bf16(y.x, y.y); r.u[3] = pack2_bf16(y.z, y.w);
    return r.s;
}

// 512 blocks x 512 threads (8 waves) = 4096 waves -> 4 waves/SIMD, 2 blocks/CU.
// Tile = 16 query rows, span 48. Waves 0..2: one 16x16 QK tile each (global->
// reg bf16 frags). All waves: preload own PV V-operands (32-wide D-slice) to
// registers pre-barrier. Softmax: 32 threads/row. PV: 2 MFMA per wave.
// Two co-resident blocks/CU interleave phases -> barrier gaps get filled.
__global__ __launch_bounds__(512) void local_attn_v7(
    const float* __restrict__ q,
    const float* __restrict__ k,
    const float* __restrict__ v,
    const int*   __restrict__ mask,
    float* __restrict__ out_v,   // [B*S*D]
    float* __restrict__ out_p)   // [B*S*WIN]
{
    __shared__ __align__(16) float          Sc[TROWS * SC_STRIDE];  // 4.35 KB
    __shared__ __align__(16) unsigned short Pt[TROWS * PT_STRIDE];  // 2.25 KB
    __shared__ int wm[SPAN];

    const int t    = threadIdx.x;
    const int lane = t & 63;
    const int w    = t >> 6;          // wave 0..7
    const int l15  = lane & 15;
    const int q4   = lane >> 4;

    const int bid  = blockIdx.x;                      // 0..511
    const int tile = ((bid & 7) << 6) | (bid >> 3);   // XCD-contiguous stripes
    const int b    = tile >> 7;                       // 128 tiles per batch
    const int s0   = (tile & 127) << 4;               // first query row

    const float* qb = q + ((size_t)b * S_LEN + s0) * D_DIM;
    const float* kb = k + (size_t)b * S_LEN * D_DIM;
    const float* vb = v + (size_t)b * S_LEN * D_DIM;

    if (t < SPAN) {
        const int idx = s0 - HALF + t;
        wm[t] = (idx >= 0 && idx < S_LEN) ? (mask[b * S_LEN + idx] != 0) : 0;
    }

    // ---- Phase A1 (waves 0..2): QK 16x16 tile, col-tile w ----
    if (w < 3) {
        const int c    = 16 * w + l15;                 // span col 0..47
        const int kidx = min(max(s0 - HALF + c, 0), S_LEN - 1);
        const float* kr = kb + (size_t)kidx * D_DIM;
        const float* qr = qb + (size_t)l15 * D_DIM;
        f32x4 acc = (f32x4){0.f, 0.f, 0.f, 0.f};
#pragma unroll
        for (int ks = 0; ks < 8; ++ks) {
            const float* pq = qr + ks * 32 + q4 * 8;
            const float* pk = kr + ks * 32 + q4 * 8;
            const short8_t aq = pack_bf16x8(*(const float4*)pq, *(const float4*)(pq + 4));
            const short8_t bk = pack_bf16x8(*(const float4*)pk, *(const float4*)(pk + 4));
            acc = __builtin_amdgcn_mfma_f32_16x16x32_bf16(aq, bk, acc, 0, 0, 0);
        }
#pragma unroll
        for (int r = 0; r < 4; ++r)
            Sc[(q4 * 4 + r) * SC_STRIDE + c] = acc[r];
    }

    // ---- Phase A2 (all waves): PV V-operand preload, D-slice [32w, 32w+32) ----
    // B-frag[nt][ks][j] = V[g = ks*32 + q4*8 + j][d = 32w + nt*16 + l15]
    // ks=1 with q4>=2 -> g>=48: P=0 there, use zero frag (no load).
    short8_t bv[2][2];
    {
        const bool act1 = (q4 < 2);
        const short8_t zfrag = {0,0,0,0,0,0,0,0};
        float vr[2][2][8];
#pragma unroll
        for (int nt = 0; nt < 2; ++nt) {
            const int d = 32 * w + nt * 16 + l15;
#pragma unroll
            for (int j = 0; j < 8; ++j) {
                const int g0   = q4 * 8 + j;
                const int idx0 = min(max(s0 - HALF + g0, 0), S_LEN - 1);
                vr[nt][0][j] = vb[(size_t)idx0 * D_DIM + d];
            }
            if (act1) {
#pragma unroll
                for (int j = 0; j < 8; ++j) {
                    const int g1   = 32 + q4 * 8 + j;   // < 48 when q4 < 2
                    const int idx1 = min(max(s0 - HALF + g1, 0), S_LEN - 1);
                    vr[nt][1][j] = vb[(size_t)idx1 * D_DIM + d];
                }
            }
        }
#pragma unroll
        for (int nt = 0; nt < 2; ++nt) {
            float4 x, y;
            x.x = vr[nt][0][0]; x.y = vr[nt][0][1]; x.z = vr[nt][0][2]; x.w = vr[nt][0][3];
            y.x = vr[nt][0][4]; y.y = vr[nt][0][5]; y.z = vr[nt][0][6]; y.w = vr[nt][0][7];
            bv[nt][0] = pack_bf16x8(x, y);
            if (act1) {
                x.x = vr[nt][1][0]; x.y = vr[nt][1][1]; x.z = vr[nt][1][2]; x.w = vr[nt][1][3];
                y.x = vr[nt][1][4]; y.y = vr[nt][1][5]; y.z = vr[nt][1][6]; y.w = vr[nt][1][7];
                bv[nt][1] = pack_bf16x8(x, y);
            } else {
                bv[nt][1] = zfrag;
            }
        }
    }
    __syncthreads();

    // ---- Phase B: softmax, row = t>>5 (0..15), thread covers cols 2e, 2e+1 ----
    {
        const int row = t >> 5;
        const int e   = t & 31;
        float vs[2];
#pragma unroll
        for (int kq = 0; kq < 2; ++kq) {
            const int c = 2 * e + kq;                   // frame col 0..63
            const int j = c - row;
            const bool inb = (j >= 0) && (j < WIN) && (c < SPAN);
            vs[kq] = inb ? (wm[c < SPAN ? c : 0] ? Sc[row * SC_STRIDE + (c < SPAN ? c : 0)] * 0.0625f
                                                 : -1e10f)
                         : -1e30f;
        }
        float m = fmaxf(vs[0], vs[1]);
        m = fmaxf(m, __shfl_xor(m, 1, 64));
        m = fmaxf(m, __shfl_xor(m, 2, 64));
        m = fmaxf(m, __shfl_xor(m, 4, 64));
        m = fmaxf(m, __shfl_xor(m, 8, 64));
        m = fmaxf(m, __shfl_xor(m, 16, 64));
        float s = 0.f;
#pragma unroll
        for (int kq = 0; kq < 2; ++kq) { vs[kq] = __expf(vs[kq] - m); s += vs[kq]; }
        s += __shfl_xor(s, 1, 64);
        s += __shfl_xor(s, 2, 64);
        s += __shfl_xor(s, 4, 64);
        s += __shfl_xor(s, 8, 64);
        s += __shfl_xor(s, 16, 64);
        const float rinv = 1.0f / s;

        float p0 = vs[0] * rinv, p1 = vs[1] * rinv;     // exact 0 out-of-band
        *(unsigned*)&Pt[row * PT_STRIDE + 2 * e] = pack2_bf16(p0, p1);
        float* prow = out_p + ((size_t)(b * S_LEN + s0 + row)) * WIN;
        const int j0 = 2 * e - row;
        if (j0 >= 0 && j0 < WIN)     prow[j0]     = p0;
        if (j0 + 1 >= 0 && j0 + 1 < WIN) prow[j0 + 1] = p1;
    }
    __syncthreads();

    // ---- Phase C: PV. Wave w -> 16 rows x D cols [32w, 32w+32) ----
    {
        const short8_t ap0 = *(const short8_t*)&Pt[l15 * PT_STRIDE + q4 * 8];
        const short8_t ap1 = *(const short8_t*)&Pt[l15 * PT_STRIDE + 32 + q4 * 8];
        float* ob = out_v + ((size_t)b * S_LEN + s0) * D_DIM;
#pragma unroll
        for (int nt = 0; nt < 2; ++nt) {
            f32x4 acc = (f32x4){0.f, 0.f, 0.f, 0.f};
            acc = __builtin_amdgcn_mfma_f32_16x16x32_bf16(ap0, bv[nt][0], acc, 0, 0, 0);
            acc = __builtin_amdgcn_mfma_f32_16x16x32_bf16(ap1, bv[nt][1], acc, 0, 0, 0);
            const int d = 32 * w + nt * 16 + l15;
#pragma unroll
            for (int r = 0; r < 4; ++r)
                ob[(size_t)(q4 * 4 + r) * D_DIM + d] = acc[r];
        }
    }
}

extern "C" void kernel_launch(void* const* d_in, const int* in_sizes, int n_in,
                              void* d_out, int out_size, void* d_ws, size_t ws_size,
                              hipStream_t stream) {
    const float* q    = (const float*)d_in[0];
    const float* k    = (const float*)d_in[1];
    const float* v    = (const float*)d_in[2];
    const int*   mask = (const int*)d_in[3];

    const int B = 4;
    float* out_v = (float*)d_out;
    float* out_p = (float*)d_out + (size_t)B * S_LEN * D_DIM;

    const int blocks = B * (S_LEN / TROWS);   // 512 blocks x 512 threads
    local_attn_v7<<<blocks, 512, 0, stream>>>(q, k, v, mask, out_v, out_p);
}